// Round 1
// baseline (71.500 us; speedup 1.0000x reference)
//
#include <hip/hip_runtime.h>

// ConditionsLayer: out[b,u] = g(u) * relu(x[b, u%64] - w1[u]) + (1-g(u)) * relu(w2[u] - x[b, u%64])
// B=1024, D=64, U=8192. Pure memory-bound elementwise-with-gather.
// Each thread produces one float4 of the output (4 consecutive u, same b).

#define B_DIM 1024
#define D_DIM 64
#define U_DIM 8192

__global__ __launch_bounds__(256) void ConditionsLayer_kernel(
    const float* __restrict__ x,   // [B, D]
    const float* __restrict__ w1,  // [U]
    const float* __restrict__ w2,  // [U]
    float* __restrict__ out)       // [B, U]
{
    const int total4 = (B_DIM * U_DIM) / 4;  // 2,097,152 float4s
    const int stride = gridDim.x * blockDim.x;

    for (int i = blockIdx.x * blockDim.x + threadIdx.x; i < total4; i += stride) {
        const int flat = i << 2;          // element index into out
        const int b    = flat >> 13;      // / U_DIM (8192)
        const int u0   = flat & (U_DIM - 1);
        const int idx0 = u0 & (D_DIM - 1);     // u % 64; quad never crosses 64-boundary (x4-aligned)
        const bool g   = ((u0 >> 6) & 1) == 0; // constant within the quad

        const float4 xv  = *reinterpret_cast<const float4*>(x  + b * D_DIM + idx0);
        const float4 w1v = *reinterpret_cast<const float4*>(w1 + u0);
        const float4 w2v = *reinterpret_cast<const float4*>(w2 + u0);

        float4 o;
        o.x = fmaxf(g ? (xv.x - w1v.x) : (w2v.x - xv.x), 0.0f);
        o.y = fmaxf(g ? (xv.y - w1v.y) : (w2v.y - xv.y), 0.0f);
        o.z = fmaxf(g ? (xv.z - w1v.z) : (w2v.z - xv.z), 0.0f);
        o.w = fmaxf(g ? (xv.w - w1v.w) : (w2v.w - xv.w), 0.0f);

        *reinterpret_cast<float4*>(out + flat) = o;
    }
}

extern "C" void kernel_launch(void* const* d_in, const int* in_sizes, int n_in,
                              void* d_out, int out_size, void* d_ws, size_t ws_size,
                              hipStream_t stream) {
    const float* x  = (const float*)d_in[0];
    const float* w1 = (const float*)d_in[1];
    const float* w2 = (const float*)d_in[2];
    float* out = (float*)d_out;

    const int total4 = (B_DIM * U_DIM) / 4;
    const int block = 256;
    int grid = (total4 + block - 1) / block;   // 8192
    if (grid > 2048) grid = 2048;              // grid-stride x4

    ConditionsLayer_kernel<<<grid, block, 0, stream>>>(x, w1, w2, out);
}

// Round 4
// 70.141 us; speedup vs baseline: 1.0194x; 1.0194x over previous
//
#include <hip/hip_runtime.h>

// ConditionsLayer: out[b,u] = g(u) ? relu(x[b,u%64] - w1[u]) : relu(w2[u] - x[b,u%64])
// B=1024, D=64, U=8192, g(u) = ((u/64) % 2 == 0). Memory-bound: 33.5 MB writes dominate.
// One 4-float vector of out per thread, exact grid (no loop). Non-temporal streaming stores.

#define B_DIM 1024
#define D_DIM 64
#define U_DIM 8192

// Native clang vector (NOT HIP_vector_type) — required by __builtin_nontemporal_store.
typedef float v4f __attribute__((ext_vector_type(4)));

__global__ __launch_bounds__(256) void ConditionsLayer_kernel(
    const float* __restrict__ x,   // [B, D]
    const float* __restrict__ w1,  // [U]
    const float* __restrict__ w2,  // [U]
    float* __restrict__ out)       // [B, U]
{
    const int i    = blockIdx.x * 256 + threadIdx.x;  // 0 .. B*U/4 - 1
    const int flat = i << 2;                          // element index into out
    const int b    = flat >> 13;                      // / U_DIM
    const int u0   = flat & (U_DIM - 1);
    const int idx0 = u0 & (D_DIM - 1);                // u % 64; quad is x4-aligned, never crosses D
    const bool g   = ((u0 >> 6) & 1) == 0;            // constant within the quad

    const v4f xv = *reinterpret_cast<const v4f*>(x + (b << 6) + idx0);
    // Only one of w1/w2 is needed per quad — select the pointer, single load.
    const v4f wv = *reinterpret_cast<const v4f*>((g ? w1 : w2) + u0);

    // g: relu(x - w); !g: relu(w - x). Branchless via sign select.
    v4f d = g ? (xv - wv) : (wv - xv);
    v4f o;
    o.x = fmaxf(d.x, 0.0f);
    o.y = fmaxf(d.y, 0.0f);
    o.z = fmaxf(d.z, 0.0f);
    o.w = fmaxf(d.w, 0.0f);

    // Streaming store: out is written once, never re-read by this kernel.
    __builtin_nontemporal_store(o, reinterpret_cast<v4f*>(out + flat));
}

extern "C" void kernel_launch(void* const* d_in, const int* in_sizes, int n_in,
                              void* d_out, int out_size, void* d_ws, size_t ws_size,
                              hipStream_t stream) {
    const float* x  = (const float*)d_in[0];
    const float* w1 = (const float*)d_in[1];
    const float* w2 = (const float*)d_in[2];
    float* out = (float*)d_out;

    const int total4 = (B_DIM * U_DIM) / 4;  // 2,097,152
    const int block  = 256;
    const int grid   = total4 / block;       // 8192 — exact, no tail

    ConditionsLayer_kernel<<<grid, block, 0, stream>>>(x, w1, w2, out);
}

// Round 10
// 70.089 us; speedup vs baseline: 1.0201x; 1.0007x over previous
//
#include <hip/hip_runtime.h>

// ConditionsLayer: out[b,u] = g(u) ? relu(x[b,u%64] - w1[u]) : relu(w2[u] - x[b,u%64])
// B=1024, D=64, U=8192, g(u) = ((u/64) % 2 == 0). Memory-bound: 33.5 MB writes dominate.
// 4 float4s per thread, wave-strided so each store instr is a coalesced 1KiB wave write.
// Grid = 2048 workgroups (256 CU x 8). Non-temporal streaming stores.

#define B_DIM 1024
#define D_DIM 64
#define U_DIM 8192

// Native clang vector (NOT HIP_vector_type) — required by __builtin_nontemporal_store.
typedef float v4f __attribute__((ext_vector_type(4)));

__global__ __launch_bounds__(256) void ConditionsLayer_kernel(
    const float* __restrict__ x,   // [B, D]
    const float* __restrict__ w1,  // [U]
    const float* __restrict__ w2,  // [U]
    float* __restrict__ out)       // [B, U]
{
    const int tid  = blockIdx.x * 256 + threadIdx.x;
    const int wave = tid >> 6;            // global wave id
    const int lane = tid & 63;
    const int q0   = (wave << 8) + lane;  // wave owns quads [wave*256, wave*256+256)

#pragma unroll
    for (int j = 0; j < 4; ++j) {
        const int q    = q0 + (j << 6);       // quad index; lane-consecutive within each j
        const int flat = q << 2;              // element index into out
        const int b    = flat >> 13;          // / U_DIM
        const int u0   = flat & (U_DIM - 1);
        const int idx0 = u0 & (D_DIM - 1);    // u % 64; quad is x4-aligned, never crosses D
        const bool g   = ((u0 >> 6) & 1) == 0;

        const v4f xv = *reinterpret_cast<const v4f*>(x + (b << 6) + idx0);
        // Only one of w1/w2 is needed per quad — select the pointer, single load.
        const v4f wv = *reinterpret_cast<const v4f*>((g ? w1 : w2) + u0);

        v4f d = g ? (xv - wv) : (wv - xv);
        v4f o;
        o.x = fmaxf(d.x, 0.0f);
        o.y = fmaxf(d.y, 0.0f);
        o.z = fmaxf(d.z, 0.0f);
        o.w = fmaxf(d.w, 0.0f);

        // Streaming store: out is written once, never re-read by this kernel.
        __builtin_nontemporal_store(o, reinterpret_cast<v4f*>(out + flat));
    }
}

extern "C" void kernel_launch(void* const* d_in, const int* in_sizes, int n_in,
                              void* d_out, int out_size, void* d_ws, size_t ws_size,
                              hipStream_t stream) {
    const float* x  = (const float*)d_in[0];
    const float* w1 = (const float*)d_in[1];
    const float* w2 = (const float*)d_in[2];
    float* out = (float*)d_out;

    const int total4 = (B_DIM * U_DIM) / 4;        // 2,097,152 float4s
    const int block  = 256;
    const int grid   = total4 / (block * 4);       // 2048 — exact, no tail

    ConditionsLayer_kernel<<<grid, block, 0, stream>>>(x, w1, w2, out);
}